// Round 9
// baseline (4358.138 us; speedup 1.0000x reference)
//
#include <hip/hip_runtime.h>
#include <math.h>

#define TT 512
#define BB 64
#define DIN 256
#define HH 512
#define DOUT 256

// x-part A tiles (hi/lo): 16 rows (batches) x 256 f16, padded rows
#define RSXU 132         // row stride in u32 (128 data + 4 pad)
#define RSXH 264         // row stride in f16
#define PST  68          // p_l row stride in f32

// LDS layout (u32 units)
#define AXH_OFF 0
#define AXL_OFF 2112     // 16*132
#define P_OFF   4224     // 128 rows x PST = 8704  (rows = wave*16 + batch)
#define B_OFF   12928    // 64 biases (gate*16 + unit)
#define C_OFF   12992    // 256 cell states (batch*16 + unit)
#define HST_HI  13248    // 128 u32 (256 u16) h-hi stage
#define HST_LO  13376    // 128 u32 h-lo stage
#define SMEM_U32 13504
#define SMEM_BYTES (SMEM_U32*4)

#define FCS 516          // fc LDS stride

typedef _Float16 f16x8 __attribute__((ext_vector_type(8)));
typedef float    f32x4 __attribute__((ext_vector_type(4)));
typedef unsigned u32x4 __attribute__((ext_vector_type(4)));

union H16  { _Float16 f; unsigned short u; };
union V16  { u32x4 u; f16x8 f; };
__device__ __forceinline__ unsigned short f16bits(_Float16 h) { H16 t; t.f = h; return t.u; }

// split x,y into f16 hi + scaled-lo (lo = (x-hi)*2048 stays in f16 normal range)
__device__ __forceinline__ void pack2(float x, float y, unsigned& hi, unsigned& lo) {
    _Float16 hx = (_Float16)x, hy = (_Float16)y;
    _Float16 lx = (_Float16)((x - (float)hx) * 2048.0f);
    _Float16 ly = (_Float16)((y - (float)hy) * 2048.0f);
    hi = (unsigned)f16bits(hx) | ((unsigned)f16bits(hy) << 16);
    lo = (unsigned)f16bits(lx) | ((unsigned)f16bits(ly) << 16);
}

// coherent (LLC) 16B load/store — the ONLY exchange path (sc0-only proven
// unsafe in R3-R5: stale L1/L2 hits tag-false-match at period 4).
__device__ __forceinline__ u32x4 ld16_cohere(const void* p) {
    u32x4 v;
    asm volatile("global_load_dwordx4 %0, %1, off sc0 sc1"
                 : "=&v"(v) : "v"(p) : "memory");
    return v;
}
__device__ __forceinline__ void st16_cohere(void* p, u32x4 v) {
    asm volatile("global_store_dwordx4 %0, %1, off sc0 sc1"
                 :: "v"(p), "v"(v) : "memory");
}
__device__ __forceinline__ void st32_cohere(unsigned* p, unsigned v) {
    asm volatile("global_store_dword %0, %1, off sc0 sc1"
                 :: "v"(p), "v"(v) : "memory");
}

// tag check: every u16 LSB of the 16B vector must equal `par`.
__device__ __forceinline__ bool tag_ok(u32x4 v, unsigned par) {
    unsigned a = v[0] & v[1] & v[2] & v[3];
    unsigned o = v[0] | v[1] | v[2] | v[3];
    unsigned x = par ? ~a : o;
    return (x & 0x00010001u) == 0u;
}

// ---------------- W fragments: fp32 global -> f16 hi/lo REGISTERS ----------------
// Wave w: ALL 4 gates x 16 units, k-slices {2w, 2w+1} (h) + x-slice w.
// Lane (m,q): B-frag col = unit m of gate g -> W row C = g*HH + u0 + m.
// 4 gates x 3 slices x (hi,lo) f16x8 = 96 VGPR.
__device__ __forceinline__ void load_w_regs(const float* __restrict__ Whh,
                                            const float* __restrict__ Wih,
                                            int u0, int w, int m, int q,
                                            f16x8 (&whi)[4][3], f16x8 (&wlo)[4][3]) {
    #pragma unroll
    for (int g = 0; g < 4; ++g) {
        const int C = g*HH + u0 + m;
        const float* rowH = Whh + (size_t)C*HH;
        const float* rowI = Wih + (size_t)C*DIN;
        #pragma unroll
        for (int sl = 0; sl < 3; ++sl) {
            const float* src = (sl < 2) ? (rowH + (2*w + sl)*32 + q*8)
                                        : (rowI + w*32 + q*8);
            float4 a = ((const float4*)src)[0];
            float4 b = ((const float4*)src)[1];
            f16x8 h8, l8; _Float16 t16;
            t16=(_Float16)a.x; h8[0]=t16; l8[0]=(_Float16)((a.x-(float)t16)*2048.0f);
            t16=(_Float16)a.y; h8[1]=t16; l8[1]=(_Float16)((a.y-(float)t16)*2048.0f);
            t16=(_Float16)a.z; h8[2]=t16; l8[2]=(_Float16)((a.z-(float)t16)*2048.0f);
            t16=(_Float16)a.w; h8[3]=t16; l8[3]=(_Float16)((a.w-(float)t16)*2048.0f);
            t16=(_Float16)b.x; h8[4]=t16; l8[4]=(_Float16)((b.x-(float)t16)*2048.0f);
            t16=(_Float16)b.y; h8[5]=t16; l8[5]=(_Float16)((b.y-(float)t16)*2048.0f);
            t16=(_Float16)b.z; h8[6]=t16; l8[6]=(_Float16)((b.z-(float)t16)*2048.0f);
            t16=(_Float16)b.w; h8[7]=t16; l8[7]=(_Float16)((b.w-(float)t16)*2048.0f);
            whi[g][sl] = h8; wlo[g][sl] = l8;
        }
    }
}

// ---------------- x staging: fp32 global -> AX hi/lo tiles (16 x 256 f16) ----------------
__device__ __forceinline__ void stage_x_f16(unsigned* __restrict__ sm32,
                                            const float* __restrict__ src, int tid) {
    for (int r = 0; r < 2; ++r) {
        int idx4 = tid + 512*r;          // 1024 float4 = 16 rows x 64
        int b = idx4 >> 6, j4 = idx4 & 63;
        float4 v = ((const float4*)(src + (size_t)b*DIN))[j4];
        unsigned h0, l0, h1, l1;
        pack2(v.x, v.y, h0, l0);
        pack2(v.z, v.w, h1, l1);
        int o = b*RSXU + 2*j4;
        sm32[AXH_OFF + o]     = h0;
        sm32[AXH_OFF + o + 1] = h1;
        sm32[AXL_OFF + o]     = l0;
        sm32[AXL_OFF + o + 1] = l1;
    }
}

__device__ __forceinline__ void stage_x_zero_f16(unsigned* __restrict__ sm32, int tid) {
    for (int r = 0; r < 2; ++r) {
        int idx = tid + 512*r;           // 1024: 16 rows x 64
        int row = idx >> 6, j = idx & 63;
        int o = row*RSXU + 2*j;
        sm32[AXH_OFF + o]     = 0u;
        sm32[AXH_OFF + o + 1] = 0u;
        sm32[AXL_OFF + o]     = 0u;
        sm32[AXL_OFF + o + 1] = 0u;
    }
}

// ---------------- persistent LSTM kernel (per-slice direct gather, progressive MFMA) ----------------
// Geometry: 4 batch-groups (g = blockIdx&3) x 16 batches; 32 producers/group
// (ij = blockIdx>>2) x 16 h-units. 128 blocks x 512 threads.
// Wave w computes ALL 4 gates over k-slices {2w,2w+1} (h, fragments loaded
// DIRECTLY from the exchange buffers per-lane with tag polling — each 16B
// fragment is exactly one producer's 16B store) + x-slice w (from LDS).
// Per-wave wait set = 4 producers (4w..4w+3); MFMA starts per-slice as data
// arrives. 8 waves' partial gate sums meet in p_l; EW sums 8 partials.
// Exchange protocol byte-identical to R6/R7 (tag-in-data, sc0sc1 both sides);
// init seeds slot0 with split-h0 (tag 0) since h always flows via global.
__global__ __launch_bounds__(512, 1)
void lstm_persist(const float* __restrict__ x, const float* __restrict__ target,
                  const float* __restrict__ c0,
                  const float* __restrict__ eWih, const float* __restrict__ eWhh,
                  const float* __restrict__ eb,
                  const float* __restrict__ dWih, const float* __restrict__ dWhh,
                  const float* __restrict__ db,
                  float* __restrict__ hs,
                  unsigned short* __restrict__ hbh,   // [2][64][512] f16-hi
                  unsigned short* __restrict__ hbl)   // [2][64][512] f16-lo
{
    extern __shared__ unsigned sm32[];
    float* p_l = (float*)(sm32 + P_OFF);
    float* b_l = (float*)(sm32 + B_OFF);
    float* c_l = (float*)(sm32 + C_OFF);
    unsigned* hst_hi = sm32 + HST_HI;
    unsigned* hst_lo = sm32 + HST_LO;

    const int tid = (int)threadIdx.x;
    const int g   = (int)(blockIdx.x & 3);     // batch group 0..3
    const int ij  = (int)(blockIdx.x >> 2);    // producer id 0..31
    const int b0  = g * 16;
    const int u0  = ij * 16;

    // ---- initial staging ----
    if (tid < 256) {
        int b = tid >> 4, u = tid & 15;
        c_l[tid] = c0[(size_t)(b0 + b)*HH + u0 + u];
    }
    if (tid < 64) b_l[tid] = eb[(tid >> 4)*HH + u0 + (tid & 15)];
    stage_x_f16(sm32, x + (size_t)b0*DIN, tid);     // x for s=0
    __syncthreads();

    const int lane = tid & 63;
    const int wid  = tid >> 6;         // wave 0..7
    const int m    = lane & 15;        // batch-row / unit-col
    const int q    = lane >> 4;        // quad

    f16x8 whi[4][3], wlo[4][3];
    load_w_regs(eWhh, eWih, u0, wid, m, q, whi, wlo);

    const _Float16* aXH = (const _Float16*)(sm32 + AXH_OFF);
    const _Float16* aXL = (const _Float16*)(sm32 + AXL_OFF);
    const int xoff = m*RSXH + wid*32 + q*8;
    const int o0 = wid*64 + q*8;       // u16 offset of h-slice 2*wid fragment
    const int o1 = o0 + 32;            // h-slice 2*wid+1

    for (int s = 0; s < 1024; ++s) {
        const int gslot = s & 1;                        // slot holding h_{s-1}
        const unsigned gpar = (unsigned)((s >> 1) & 1); // its tag

        f32x4 ahh[4], alo[4];
        #pragma unroll
        for (int gg = 0; gg < 4; ++gg) {
            ahh[gg] = (f32x4){0.f,0.f,0.f,0.f};
            alo[gg] = (f32x4){0.f,0.f,0.f,0.f};
        }

        // ---- P1: x-part MFMA (local LDS; overlaps producers' publish flight) ----
        {
            f16x8 xh = *(const f16x8*)(aXH + xoff);
            f16x8 xl = *(const f16x8*)(aXL + xoff);
            #pragma unroll
            for (int gg = 0; gg < 4; ++gg) {
                ahh[gg] = __builtin_amdgcn_mfma_f32_16x16x32_f16(xh, whi[gg][2], ahh[gg], 0, 0, 0);
                alo[gg] = __builtin_amdgcn_mfma_f32_16x16x32_f16(xl, whi[gg][2],
                          __builtin_amdgcn_mfma_f32_16x16x32_f16(xh, wlo[gg][2], alo[gg], 0, 0, 0), 0, 0, 0);
            }
        }

        // ---- P2: per-lane direct gather of h-fragments + progressive MFMA ----
        {
            const unsigned short* SH = hbh + (size_t)gslot*BB*HH + (size_t)(b0 + m)*HH;
            const unsigned short* SL = hbl + (size_t)gslot*BB*HH + (size_t)(b0 + m)*HH;
            u32x4 a0h = {0,0,0,0}, a0l = {0,0,0,0}, a1h = {0,0,0,0}, a1l = {0,0,0,0};
            unsigned lp = 3u;   // lane-local: fragment sets still unverified
            unsigned wp = 3u;   // wave-level: slices not yet MFMA'd
            do {
                if (lp & 1u) { a0h = ld16_cohere(SH + o0); a0l = ld16_cohere(SL + o0); }
                if (lp & 2u) { a1h = ld16_cohere(SH + o1); a1l = ld16_cohere(SL + o1); }
                asm volatile("s_waitcnt vmcnt(0)"
                             : "+v"(a0h), "+v"(a0l), "+v"(a1h), "+v"(a1l) :: "memory");
                if ((lp & 1u) && tag_ok(a0h, gpar) && tag_ok(a0l, gpar)) lp &= ~1u;
                if ((lp & 2u) && tag_ok(a1h, gpar) && tag_ok(a1l, gpar)) lp &= ~2u;
                if ((wp & 1u) && __all((lp & 1u) == 0u)) {
                    V16 vh, vl; vh.u = a0h; vl.u = a0l;
                    #pragma unroll
                    for (int gg = 0; gg < 4; ++gg) {
                        ahh[gg] = __builtin_amdgcn_mfma_f32_16x16x32_f16(vh.f, whi[gg][0], ahh[gg], 0, 0, 0);
                        alo[gg] = __builtin_amdgcn_mfma_f32_16x16x32_f16(vl.f, whi[gg][0],
                                  __builtin_amdgcn_mfma_f32_16x16x32_f16(vh.f, wlo[gg][0], alo[gg], 0, 0, 0), 0, 0, 0);
                    }
                    wp &= ~1u;
                }
                if ((wp & 2u) && __all((lp & 2u) == 0u)) {
                    V16 vh, vl; vh.u = a1h; vl.u = a1l;
                    #pragma unroll
                    for (int gg = 0; gg < 4; ++gg) {
                        ahh[gg] = __builtin_amdgcn_mfma_f32_16x16x32_f16(vh.f, whi[gg][1], ahh[gg], 0, 0, 0);
                        alo[gg] = __builtin_amdgcn_mfma_f32_16x16x32_f16(vl.f, whi[gg][1],
                                  __builtin_amdgcn_mfma_f32_16x16x32_f16(vh.f, wlo[gg][1], alo[gg], 0, 0, 0), 0, 0, 0);
                    }
                    wp &= ~2u;
                }
            } while (wp);
        }

        // ---- P3: write partial gate sums ----
        {
            const float sc = 1.0f/2048.0f;
            float* pb = p_l + (wid*16 + q*4)*PST + m;
            #pragma unroll
            for (int gg = 0; gg < 4; ++gg)
                #pragma unroll
                for (int i = 0; i < 4; ++i)
                    pb[i*PST + gg*16] = ahh[gg][i] + alo[gg][i]*sc;
        }
        __syncthreads();

        const unsigned ppar = (unsigned)(((s + 1) >> 1) & 1);   // publish tag bit

        // ---- P4: elementwise LSTM update -> LDS h-stage (tagged split-f16) ----
        float hval = 0.f;
        if (tid < 256) {
            const int b = tid >> 4, u = tid & 15;
            float gi = b_l[u], gf = b_l[16 + u], gg2 = b_l[32 + u], go = b_l[48 + u];
            #pragma unroll
            for (int w = 0; w < 8; ++w) {
                const float* pp = p_l + (size_t)(w*16 + b)*PST;
                gi  += pp[u];
                gf  += pp[16 + u];
                gg2 += pp[32 + u];
                go  += pp[48 + u];
            }
            float ii = 1.f/(1.f + expf(-gi));
            float ff = 1.f/(1.f + expf(-gf));
            float g2 = tanhf(gg2);
            float oo = 1.f/(1.f + expf(-go));
            float c  = ff*c_l[tid] + ii*g2;
            c_l[tid] = c;
            hval = oo*tanhf(c);
            _Float16 hh16 = (_Float16)hval;
            unsigned uh = ((unsigned)f16bits(hh16) & 0xFFFEu) | ppar;
            H16 t16; t16.u = (unsigned short)uh;
            _Float16 hl16 = (_Float16)((hval - (float)t16.f) * 2048.0f);
            unsigned ul = ((unsigned)f16bits(hl16) & 0xFFFEu) | ppar;
            ((unsigned short*)hst_hi)[tid] = (unsigned short)uh;   // tid = b*16+u
            ((unsigned short*)hst_lo)[tid] = (unsigned short)ul;
        }
        __syncthreads();

        // ---- P5: publish: 64 coherent 16B stores (16 batches x hi/lo x 2 halves) ----
        if (tid < 64) {
            // order prior-step publishes before this one (waits on ~1-step-old
            // traffic only -> essentially free); guarantees period-4 tag safety.
            asm volatile("s_waitcnt vmcnt(0)" ::: "memory");
            const int b = tid >> 2, part = tid & 3;
            const int isLo = part >> 1, h16 = part & 1;
            u32x4 v = *(const u32x4*)((isLo ? hst_lo : hst_hi) + b*8 + h16*4);
            unsigned short* base = (isLo ? hbl : hbh)
                + ((size_t)((s & 1) ^ 1)*BB + b0 + b)*HH + u0 + h16*8;
            st16_cohere(base, v);
        }

        // ---- P6: off-critical-path tails ----
        if (s >= 512 && tid < 256) {
            int b = tid >> 4, u = tid & 15;
            hs[((size_t)(s - 512)*BB + (b0 + b))*HH + (u0 + u)] = hval;
        }
        if (s == 511) {
            load_w_regs(dWhh, dWih, u0, wid, m, q, whi, wlo);   // decoder W
            if (tid < 64) b_l[tid] = db[(tid >> 4)*HH + u0 + (tid & 15)];
        }
        {
            int ns = s + 1;
            if (ns < 1024) {
                if (ns == 512)       stage_x_zero_f16(sm32, tid);
                else if (ns < 512)   stage_x_f16(sm32, x + ((size_t)ns*BB + b0)*DIN, tid);
                else                 stage_x_f16(sm32, target + ((size_t)(ns - 513)*BB + b0)*DOUT, tid);
            }
        }
        __syncthreads();   // x_{s+1} staged; p_l reusable next iteration
    }
}

// ---------------- FC (logits) kernel ----------------
__global__ __launch_bounds__(256, 1)
void fc_kernel(const float* __restrict__ hs, const float* __restrict__ W,
               const float* __restrict__ bias, float* __restrict__ out)
{
    extern __shared__ float sm[];
    float* hs_l = sm;              // 16 x FCS
    float* w_l  = sm + 16*FCS;     // 32 x FCS

    const int tid = (int)threadIdx.x;
    const int rb = (int)(blockIdx.x >> 3);
    const int cb = (int)(blockIdx.x & 7);

    for (int r = 0; r < 8; ++r) {
        int id = tid + 256*r;
        int b = id >> 7, j = id & 127;
        float4 v = ((const float4*)(hs + (size_t)(rb*16 + b)*HH))[j];
        *(float4*)(hs_l + b*FCS + 4*j) = v;
    }
    for (int r = 0; r < 16; ++r) {
        int id = tid + 256*r;
        int c = id >> 7, j = id & 127;
        float4 v = ((const float4*)(W + (size_t)(cb*32 + c)*HH))[j];
        *(float4*)(w_l + c*FCS + 4*j) = v;
    }
    __syncthreads();

    const int kc = tid & 7, bt = (tid >> 3) & 3, ct = tid >> 5;
    float acc[4][4] = {};
    const float* ap = hs_l + (bt*4)*FCS + 4*kc;
    const float* wp = w_l  + (ct*4)*FCS + 4*kc;
    #pragma unroll 4
    for (int i = 0; i < 16; ++i) {
        float4 av[4], wv[4];
        #pragma unroll
        for (int q = 0; q < 4; ++q) av[q] = *(const float4*)(ap + q*FCS + 32*i);
        #pragma unroll
        for (int q = 0; q < 4; ++q) wv[q] = *(const float4*)(wp + q*FCS + 32*i);
        #pragma unroll
        for (int b2 = 0; b2 < 4; ++b2)
            #pragma unroll
            for (int c2 = 0; c2 < 4; ++c2)
                acc[b2][c2] += av[b2].x*wv[c2].x + av[b2].y*wv[c2].y
                             + av[b2].z*wv[c2].z + av[b2].w*wv[c2].w;
    }
    #pragma unroll
    for (int b2 = 0; b2 < 4; ++b2)
        #pragma unroll
        for (int c2 = 0; c2 < 4; ++c2) {
            float v = acc[b2][c2];
            v += __shfl_xor(v, 1, 64);
            v += __shfl_xor(v, 2, 64);
            v += __shfl_xor(v, 4, 64);
            acc[b2][c2] = v;
        }
    if (kc == 0) {
        #pragma unroll
        for (int b2 = 0; b2 < 4; ++b2)
            #pragma unroll
            for (int c2 = 0; c2 < 4; ++c2) {
                int row = rb*16 + bt*4 + b2;
                int col = cb*32 + ct*4 + c2;
                out[(size_t)row*DOUT + col] = acc[b2][c2] + bias[col];
            }
    }
}

// ---------------- in-place softmax over last dim (256) ----------------
__global__ __launch_bounds__(256, 1)
void softmax_kernel(float* __restrict__ out)
{
    int row  = (int)blockIdx.x * 4 + ((int)threadIdx.x >> 6);
    int lane = (int)threadIdx.x & 63;
    float4 v = ((const float4*)(out + (size_t)row*DOUT))[lane];
    float m = fmaxf(fmaxf(v.x, v.y), fmaxf(v.z, v.w));
    #pragma unroll
    for (int d = 1; d < 64; d <<= 1) m = fmaxf(m, __shfl_xor(m, d, 64));
    float ex = expf(v.x - m), ey = expf(v.y - m), ez = expf(v.z - m), ew = expf(v.w - m);
    float ssum = ex + ey + ez + ew;
    #pragma unroll
    for (int d = 1; d < 64; d <<= 1) ssum += __shfl_xor(ssum, d, 64);
    float inv = 1.f / ssum;
    float4 o = make_float4(ex*inv, ey*inv, ez*inv, ew*inv);
    ((float4*)(out + (size_t)row*DOUT))[lane] = o;
}

// ---------------- exchange-buffer init (ws poisoned 0xAA before every call) ----------------
// Slot0 = split-h0 with every u16 LSB forced to 0 (gather at s=0 expects tag 0).
// Slot1 = LSB 1 everywhere (first gathered at s=1 expecting tag 0 -> mismatch
// until the s=0 publish lands). sc0sc1: init state lives at the LLC.
__global__ void init_kernel(const float* __restrict__ h0,
                            unsigned* __restrict__ hbh32, unsigned* __restrict__ hbl32)
{
    int i = (int)blockIdx.x * 256 + (int)threadIdx.x;   // 0..16383 = u32 idx in slot0
    float x0 = h0[2*i], x1 = h0[2*i + 1];
    _Float16 ha = (_Float16)x0;
    unsigned ua = (unsigned)f16bits(ha) & 0xFFFEu;
    H16 ta; ta.u = (unsigned short)ua;
    unsigned la = (unsigned)f16bits((_Float16)((x0 - (float)ta.f)*2048.0f)) & 0xFFFEu;
    _Float16 hb = (_Float16)x1;
    unsigned ub = (unsigned)f16bits(hb) & 0xFFFEu;
    H16 tb; tb.u = (unsigned short)ub;
    unsigned lb = (unsigned)f16bits((_Float16)((x1 - (float)tb.f)*2048.0f)) & 0xFFFEu;
    st32_cohere(hbh32 + i, ua | (ub << 16));
    st32_cohere(hbl32 + i, la | (lb << 16));
    st32_cohere(hbh32 + 16384 + i, 0x00010001u);
    st32_cohere(hbl32 + 16384 + i, 0x00010001u);
}

// ---------------- launch ----------------
extern "C" void kernel_launch(void* const* d_in, const int* in_sizes, int n_in,
                              void* d_out, int out_size, void* d_ws, size_t ws_size,
                              hipStream_t stream) {
    (void)in_sizes; (void)n_in; (void)out_size; (void)ws_size;
    const float* x      = (const float*)d_in[0];
    const float* target = (const float*)d_in[1];
    const float* h0     = (const float*)d_in[2];
    const float* c0     = (const float*)d_in[3];
    const float* eWih   = (const float*)d_in[4];
    const float* eWhh   = (const float*)d_in[5];
    const float* eb     = (const float*)d_in[6];
    const float* dWih   = (const float*)d_in[7];
    const float* dWhh   = (const float*)d_in[8];
    const float* db     = (const float*)d_in[9];
    const float* fcW    = (const float*)d_in[10];
    const float* fcb    = (const float*)d_in[11];
    float* out = (float*)d_out;

    float* hs = (float*)d_ws + 1024;                    // [T*B*H] decoder hidden
    unsigned short* hbh = (unsigned short*)(hs + (size_t)TT*BB*HH);  // [2][64][512] hi
    unsigned short* hbl = hbh + (size_t)2*BB*HH;                     // [2][64][512] lo

    init_kernel<<<dim3(64), dim3(256), 0, stream>>>(h0, (unsigned*)hbh, (unsigned*)hbl);

    lstm_persist<<<dim3(128), dim3(512), SMEM_BYTES, stream>>>(
        x, target, c0, eWih, eWhh, eb, dWih, dWhh, db, hs, hbh, hbl);

    size_t lds_fc = (size_t)(48*FCS) * sizeof(float);   // ~99 KB
    fc_kernel<<<dim3(16384), dim3(256), lds_fc, stream>>>(hs, fcW, fcb, out);

    softmax_kernel<<<dim3(8192), dim3(256), 0, stream>>>(out);
}